// Round 11
// baseline (139.965 us; speedup 1.0000x reference)
//
#include <hip/hip_runtime.h>
#include <math.h>

#define N_NODES 20000
#define N_EDGES 200000
#define WIDTH   256
#define MAXDEG  64
#define SCALE_F 0.17677669529663687f

typedef _Float16 half8 __attribute__((ext_vector_type(8)));
typedef _Float16 half4 __attribute__((ext_vector_type(4)));
typedef float f32x4 __attribute__((ext_vector_type(4)));

// ---- zero cnt (N_NODES ints = 80 KB) ----
__global__ __launch_bounds__(256) void zero_cnt(int* __restrict__ p)
{
    int i = blockIdx.x * 256 + threadIdx.x;
    if (i < N_NODES / 4) reinterpret_cast<int4*>(p)[i] = make_int4(0, 0, 0, 0);
}

// column remap: q | kv-interleaved(4) | r  within the 1024-wide output row
__device__ __forceinline__ int col_map(int c) {
    if (c < 256 || c >= 768) return c;
    int d = c & 255;
    return 256 + ((d >> 2) << 3) + ((c >= 512) ? 4 : 0) + (d & 3);
}

// ---- fused prep: Bt1, Bt2 (col_map'd rows), ep1, ep2, x->fp16, edge bucketing ----
#define NB_BT1  512
#define NB_BT2  1024
#define NB_EP   64
#define NB_CVT  2500
#define NB_EDGE 782
#define NB_PREP (NB_BT1 + NB_BT2 + 2*NB_EP + NB_CVT + NB_EDGE)

__global__ __launch_bounds__(256) void prep_all(
    const float* __restrict__ Wq1, const float* __restrict__ Wk1,
    const float* __restrict__ Wv1, const float* __restrict__ Wr1,
    const float* __restrict__ Wq2, const float* __restrict__ Wk2,
    const float* __restrict__ Wv2, const float* __restrict__ Wr2,
    const float* __restrict__ rel, const float* __restrict__ We1,
    const float* __restrict__ We2, const float* __restrict__ x,
    const int* __restrict__ esrc, const int* __restrict__ edst,
    const int* __restrict__ etyp,
    _Float16* __restrict__ Bt1, _Float16* __restrict__ Bt2,
    _Float16* __restrict__ ep1, _Float16* __restrict__ ep2,
    _Float16* __restrict__ xh, int* __restrict__ cnt, int* __restrict__ se)
{
    const int b = blockIdx.x, tid = threadIdx.x;
    if (b < NB_BT1) {
        int idx = b * 256 + tid;
        int c = idx >> 7, k = idx & 127;
        const float* W = (c < 256) ? Wq1 : (c < 512) ? Wk1 : (c < 768) ? Wv1 : Wr1;
        Bt1[col_map(c) * 128 + k] = (_Float16)W[k * WIDTH + (c & 255)];
    } else if (b < NB_BT1 + NB_BT2) {
        int idx = (b - NB_BT1) * 256 + tid;
        int c = idx >> 8, k = idx & 255;
        const float* W = (c < 256) ? Wq2 : (c < 512) ? Wk2 : (c < 768) ? Wv2 : Wr2;
        Bt2[col_map(c) * 256 + k] = (_Float16)W[k * WIDTH + (c & 255)];
    } else if (b < NB_BT1 + NB_BT2 + 2 * NB_EP) {
        int lb = b - (NB_BT1 + NB_BT2);
        const float* We = (lb < NB_EP) ? We1 : We2;
        _Float16* ep = (lb < NB_EP) ? ep1 : ep2;
        int r = lb & 63, c = tid;
        float acc = 0.f;
        #pragma unroll
        for (int p = 0; p < 32; ++p) acc += rel[r * 32 + p] * We[p * WIDTH + c];
        ep[r * WIDTH + c] = (_Float16)acc;
    } else if (b < NB_BT1 + NB_BT2 + 2 * NB_EP + NB_CVT) {
        int i = (b - (NB_BT1 + NB_BT2 + 2 * NB_EP)) * 256 + tid;
        float4 v = reinterpret_cast<const float4*>(x)[i];
        half4 h; h[0] = (_Float16)v.x; h[1] = (_Float16)v.y;
        h[2] = (_Float16)v.z; h[3] = (_Float16)v.w;
        reinterpret_cast<half4*>(xh)[i] = h;
    } else {
        // direct fixed-stride bucketing by destination
        int e = (b - (NB_BT1 + NB_BT2 + 2 * NB_EP + NB_CVT)) * 256 + tid;
        if (e < N_EDGES) {
            int d = edst[e];
            int pos = atomicAdd(&cnt[d], 1);
            if (pos < MAXDEG)
                se[d * MAXDEG + pos] = esrc[e] | (etyp[e] << 20);
        }
    }
}

// ---- MFMA fp16 GEMM (round-9 proven shape): 128x128 tile, 256 thr, BK=64 ----
// C[n x 1024] = A[n x K] @ Bt[1024 x K]; Bt rows already col_map-permuted.
// A and B tiles in LDS (XOR-swizzled), reg-prefetch double buffer.
template<int K>
__global__ __launch_bounds__(256) void gemm_lds(const _Float16* __restrict__ A,
    const _Float16* __restrict__ Bt, _Float16* __restrict__ C, int n)
{
    __shared__ __align__(16) _Float16 smem[128 * 128];   // 32 KB
    _Float16* As = smem;          // [128][64] swizzled
    _Float16* Bs = smem + 8192;   // [128][64] swizzled
    const int tid = threadIdx.x;
    const int wave = tid >> 6, lane = tid & 63;
    const int wr = wave >> 1, wc = wave & 1;
    const int row0 = blockIdx.x * 128;
    const int colbase0 = blockIdx.y * 128;
    const int colbase = colbase0 + wc * 64;
    const int lr = lane & 15;
    const int kg = lane >> 4;
    const int srow = tid >> 3;         // 0..31 (+32*s)
    const int scg  = tid & 7;          // 8-half chunk
    f32x4 acc[4][4] = {};
    half8 stgA[4], stgB[4];
    #pragma unroll
    for (int s = 0; s < 4; ++s) {
        int r = srow + s * 32;
        int ar = row0 + r; if (ar >= n) ar = n - 1;
        stgA[s] = *reinterpret_cast<const half8*>(&A[(size_t)ar * K + scg * 8]);
        stgB[s] = *reinterpret_cast<const half8*>(&Bt[(size_t)(colbase0 + r) * K + scg * 8]);
    }
    const int nk = K >> 6;
    for (int t = 0; t < nk; ++t) {
        #pragma unroll
        for (int s = 0; s < 4; ++s) {
            int r = srow + s * 32;
            int sw = (scg * 8) ^ ((r & 7) << 3);
            *reinterpret_cast<half8*>(&As[r * 64 + sw]) = stgA[s];
            *reinterpret_cast<half8*>(&Bs[r * 64 + sw]) = stgB[s];
        }
        __syncthreads();
        if (t + 1 < nk) {
            #pragma unroll
            for (int s = 0; s < 4; ++s) {
                int r = srow + s * 32;
                int ar = row0 + r; if (ar >= n) ar = n - 1;
                stgA[s] = *reinterpret_cast<const half8*>(&A[(size_t)ar * K + (t + 1) * 64 + scg * 8]);
                stgB[s] = *reinterpret_cast<const half8*>(&Bt[(size_t)(colbase0 + r) * K + (t + 1) * 64 + scg * 8]);
            }
        }
        #pragma unroll
        for (int ks = 0; ks < 2; ++ks) {
            half8 a[4], b[4];
            #pragma unroll
            for (int nn = 0; nn < 4; ++nn) {
                int cc = wc * 64 + nn * 16 + lr;
                b[nn] = *reinterpret_cast<const half8*>(&Bs[cc * 64 + ((ks * 32 + kg * 8) ^ ((cc & 7) << 3))]);
            }
            #pragma unroll
            for (int m = 0; m < 4; ++m) {
                int r = wr * 64 + m * 16 + lr;
                a[m] = *reinterpret_cast<const half8*>(&As[r * 64 + ((ks * 32 + kg * 8) ^ ((r & 7) << 3))]);
            }
            // swapped operands: lane holds row lr, 4 consecutive cols per acc reg group
            #pragma unroll
            for (int m = 0; m < 4; ++m)
                #pragma unroll
                for (int nn = 0; nn < 4; ++nn)
                    acc[m][nn] = __builtin_amdgcn_mfma_f32_16x16x32_f16(b[nn], a[m], acc[m][nn], 0, 0, 0);
        }
        __syncthreads();
    }
    // epilogue: per-wave 64x64 fp16 tile in LDS, then coalesced 16B stores
    _Float16* tile = &smem[wave * 4096];
    #pragma unroll
    for (int m = 0; m < 4; ++m) {
        int rr = m * 16 + lr;
        int e = (rr & 7) << 1;
        #pragma unroll
        for (int nn = 0; nn < 4; ++nn) {
            int ch = (nn * 4 + kg) ^ e;
            half4 v4;
            v4[0] = (_Float16)acc[m][nn][0];
            v4[1] = (_Float16)acc[m][nn][1];
            v4[2] = (_Float16)acc[m][nn][2];
            v4[3] = (_Float16)acc[m][nn][3];
            *reinterpret_cast<half4*>(&tile[rr * 64 + ch * 4]) = v4;
        }
    }
    const int cp = lane & 7;
    const int r8 = lane >> 3;
    #pragma unroll
    for (int p = 0; p < 8; ++p) {
        int rr = p * 8 + r8;
        int s = cp ^ (rr & 7);
        half8 v = *reinterpret_cast<const half8*>(&tile[rr * 64 + s * 8]);
        int row = row0 + wr * 64 + rr;
        if (row < n)
            *reinterpret_cast<half8*>(&C[(size_t)row * 1024 + colbase + cp * 8]) = v;
    }
}

// ---- fused per-node flash-style edge softmax; EP cached in LDS ----
// QKVR row (1024 halves): q[0,256) | kv interleaved-by-4 [256,768) | r[768,1024).
#define EDGE_DOT(kv, e0, e1, e2, e3, dd)                                     \
    float dd = qx * ((float)kv[0] + e0) + qy * ((float)kv[1] + e1)           \
             + qz * ((float)kv[2] + e2) + qw * ((float)kv[3] + e3);          \
    dd += __shfl_xor(dd, 1); dd += __shfl_xor(dd, 2); dd += __shfl_xor(dd, 4);

template<bool FINAL>
__global__ __launch_bounds__(256) void node_attn(
    const _Float16* __restrict__ QKVR, const _Float16* __restrict__ EP,
    const int* __restrict__ cnt, const int* __restrict__ se,
    _Float16* __restrict__ hout,
    const float* __restrict__ Wo, const float* __restrict__ bo,
    const float* __restrict__ cent, const float* __restrict__ gamma,
    const float* __restrict__ beta, float* __restrict__ out, int n)
{
    __shared__ __align__(16) _Float16 eps[64 * WIDTH];   // 32 KB rel-proj table
    {
        const int t = threadIdx.x;
        #pragma unroll
        for (int j = 0; j < 8; ++j) {
            int idx = (j * 256 + t) * 8;
            *reinterpret_cast<half8*>(&eps[idx]) =
                *reinterpret_cast<const half8*>(&EP[idx]);
        }
    }
    __syncthreads();
    int node = blockIdx.x * 4 + (threadIdx.x >> 6);
    if (node >= n) return;
    int lane = threadIdx.x & 63;
    const int l4 = lane * 4, l8 = lane * 8;
    half4 qh = *reinterpret_cast<const half4*>(&QKVR[(size_t)node * 1024 + l4]);
    float qx = qh[0], qy = qh[1], qz = qh[2], qw = qh[3];
    int deg = cnt[node]; if (deg > MAXDEG) deg = MAXDEG;
    const int* lst = &se[node * MAXDEG];
    float m = -INFINITY, s = 0.f;
    float ax = 0.f, ay = 0.f, az = 0.f, aw = 0.f;
    int i = 0;
    for (; i + 3 < deg; i += 4) {
        int4 pp = *reinterpret_cast<const int4*>(&lst[i]);
        int p0 = pp.x, p1 = pp.y, p2 = pp.z, p3 = pp.w;
        half8 kv0 = *reinterpret_cast<const half8*>(&QKVR[(size_t)(p0 & 0xFFFFF) * 1024 + 256 + l8]);
        half8 kv1 = *reinterpret_cast<const half8*>(&QKVR[(size_t)(p1 & 0xFFFFF) * 1024 + 256 + l8]);
        half8 kv2 = *reinterpret_cast<const half8*>(&QKVR[(size_t)(p2 & 0xFFFFF) * 1024 + 256 + l8]);
        half8 kv3 = *reinterpret_cast<const half8*>(&QKVR[(size_t)(p3 & 0xFFFFF) * 1024 + 256 + l8]);
        half4 e0 = *reinterpret_cast<const half4*>(&eps[(p0 >> 20) * WIDTH + l4]);
        half4 e1 = *reinterpret_cast<const half4*>(&eps[(p1 >> 20) * WIDTH + l4]);
        half4 e2 = *reinterpret_cast<const half4*>(&eps[(p2 >> 20) * WIDTH + l4]);
        half4 e3 = *reinterpret_cast<const half4*>(&eps[(p3 >> 20) * WIDTH + l4]);
        float e00 = e0[0], e01 = e0[1], e02 = e0[2], e03 = e0[3];
        float e10 = e1[0], e11 = e1[1], e12 = e1[2], e13 = e1[3];
        float e20 = e2[0], e21 = e2[1], e22 = e2[2], e23 = e2[3];
        float e30 = e3[0], e31 = e3[1], e32 = e3[2], e33 = e3[3];
        EDGE_DOT(kv0, e00, e01, e02, e03, d0)
        EDGE_DOT(kv1, e10, e11, e12, e13, d1)
        EDGE_DOT(kv2, e20, e21, e22, e23, d2)
        EDGE_DOT(kv3, e30, e31, e32, e33, d3)
        float sc0 = d0 * SCALE_F, sc1 = d1 * SCALE_F;
        float sc2 = d2 * SCALE_F, sc3 = d3 * SCALE_F;
        float mnew = fmaxf(m, fmaxf(fmaxf(sc0, sc1), fmaxf(sc2, sc3)));
        float f  = __expf(m - mnew);
        float w0 = __expf(sc0 - mnew);
        float w1 = __expf(sc1 - mnew);
        float w2 = __expf(sc2 - mnew);
        float w3 = __expf(sc3 - mnew);
        s = s * f + (w0 + w1) + (w2 + w3);
        ax = ax * f + w0 * ((float)kv0[4] + e00) + w1 * ((float)kv1[4] + e10)
                    + w2 * ((float)kv2[4] + e20) + w3 * ((float)kv3[4] + e30);
        ay = ay * f + w0 * ((float)kv0[5] + e01) + w1 * ((float)kv1[5] + e11)
                    + w2 * ((float)kv2[5] + e21) + w3 * ((float)kv3[5] + e31);
        az = az * f + w0 * ((float)kv0[6] + e02) + w1 * ((float)kv1[6] + e12)
                    + w2 * ((float)kv2[6] + e22) + w3 * ((float)kv3[6] + e32);
        aw = aw * f + w0 * ((float)kv0[7] + e03) + w1 * ((float)kv1[7] + e13)
                    + w2 * ((float)kv2[7] + e23) + w3 * ((float)kv3[7] + e33);
        m = mnew;
    }
    for (; i + 1 < deg; i += 2) {
        int p0 = lst[i], p1 = lst[i + 1];
        half8 kv0 = *reinterpret_cast<const half8*>(&QKVR[(size_t)(p0 & 0xFFFFF) * 1024 + 256 + l8]);
        half8 kv1 = *reinterpret_cast<const half8*>(&QKVR[(size_t)(p1 & 0xFFFFF) * 1024 + 256 + l8]);
        half4 e0 = *reinterpret_cast<const half4*>(&eps[(p0 >> 20) * WIDTH + l4]);
        half4 e1 = *reinterpret_cast<const half4*>(&eps[(p1 >> 20) * WIDTH + l4]);
        float e00 = e0[0], e01 = e0[1], e02 = e0[2], e03 = e0[3];
        float e10 = e1[0], e11 = e1[1], e12 = e1[2], e13 = e1[3];
        EDGE_DOT(kv0, e00, e01, e02, e03, d0)
        EDGE_DOT(kv1, e10, e11, e12, e13, d1)
        float sc0 = d0 * SCALE_F, sc1 = d1 * SCALE_F;
        float mnew = fmaxf(m, fmaxf(sc0, sc1));
        float f  = __expf(m - mnew);
        float w0 = __expf(sc0 - mnew);
        float w1 = __expf(sc1 - mnew);
        s = s * f + w0 + w1;
        ax = ax * f + w0 * ((float)kv0[4] + e00) + w1 * ((float)kv1[4] + e10);
        ay = ay * f + w0 * ((float)kv0[5] + e01) + w1 * ((float)kv1[5] + e11);
        az = az * f + w0 * ((float)kv0[6] + e02) + w1 * ((float)kv1[6] + e12);
        aw = aw * f + w0 * ((float)kv0[7] + e03) + w1 * ((float)kv1[7] + e13);
        m = mnew;
    }
    if (i < deg) {
        int p0 = lst[i];
        half8 kv0 = *reinterpret_cast<const half8*>(&QKVR[(size_t)(p0 & 0xFFFFF) * 1024 + 256 + l8]);
        half4 e0 = *reinterpret_cast<const half4*>(&eps[(p0 >> 20) * WIDTH + l4]);
        float e00 = e0[0], e01 = e0[1], e02 = e0[2], e03 = e0[3];
        EDGE_DOT(kv0, e00, e01, e02, e03, d0)
        float sc0 = d0 * SCALE_F;
        float mnew = fmaxf(m, sc0);
        float f  = __expf(m - mnew);
        float w0 = __expf(sc0 - mnew);
        s = s * f + w0;
        ax = ax * f + w0 * ((float)kv0[4] + e00);
        ay = ay * f + w0 * ((float)kv0[5] + e01);
        az = az * f + w0 * ((float)kv0[6] + e02);
        aw = aw * f + w0 * ((float)kv0[7] + e03);
        m = mnew;
    }
    float inv = 1.f / (s + 1e-9f);
    half4 rh = *reinterpret_cast<const half4*>(&QKVR[(size_t)node * 1024 + 768 + l4]);
    float h0 = ax * inv + (float)rh[0];
    float h1 = ay * inv + (float)rh[1];
    float h2 = az * inv + (float)rh[2];
    float h3 = aw * inv + (float)rh[3];
    h0 = h0 > 0.f ? h0 : __expf(h0) - 1.f;
    h1 = h1 > 0.f ? h1 : __expf(h1) - 1.f;
    h2 = h2 > 0.f ? h2 : __expf(h2) - 1.f;
    h3 = h3 > 0.f ? h3 : __expf(h3) - 1.f;
    if (FINAL) {
        float4 wv = *reinterpret_cast<const float4*>(&Wo[l4]);
        float p = h0 * wv.x + h1 * wv.y + h2 * wv.z + h3 * wv.w;
        #pragma unroll
        for (int o = 1; o < 64; o <<= 1) p += __shfl_xor(p, o);
        if (lane == 0) {
            float logit = p + bo[0];
            float scale = cent[node] * gamma[0] + beta[0];
            out[node] = fmaxf(scale * logit, 0.f);
        }
    } else {
        half4 hv;
        hv[0] = (_Float16)h0; hv[1] = (_Float16)h1;
        hv[2] = (_Float16)h2; hv[3] = (_Float16)h3;
        *reinterpret_cast<half4*>(&hout[(size_t)node * WIDTH + l4]) = hv;
    }
}

extern "C" void kernel_launch(void* const* d_in, const int* in_sizes, int n_in,
                              void* d_out, int out_size, void* d_ws, size_t ws_size,
                              hipStream_t stream) {
    const float* x    = (const float*)d_in[0];
    const float* cent = (const float*)d_in[1];
    const float* rel  = (const float*)d_in[2];
    const float* Wq1  = (const float*)d_in[3];
    const float* Wk1  = (const float*)d_in[4];
    const float* Wv1  = (const float*)d_in[5];
    const float* We1  = (const float*)d_in[6];
    const float* Wr1  = (const float*)d_in[7];
    const float* Wq2  = (const float*)d_in[8];
    const float* Wk2  = (const float*)d_in[9];
    const float* Wv2  = (const float*)d_in[10];
    const float* We2  = (const float*)d_in[11];
    const float* Wr2  = (const float*)d_in[12];
    const float* Wo   = (const float*)d_in[13];
    const float* bo   = (const float*)d_in[14];
    const float* gam  = (const float*)d_in[15];
    const float* bet  = (const float*)d_in[16];
    const int* esrc   = (const int*)d_in[17];
    const int* edst   = (const int*)d_in[18];
    const int* etyp   = (const int*)d_in[19];
    float* out = (float*)d_out;

    char* wsb = (char*)d_ws;
    size_t off = 0;
    auto alloc = [&](size_t bytes) { void* p = wsb + off; off += (bytes + 255) & ~(size_t)255; return p; };
    _Float16* QKVR = (_Float16*)alloc((size_t)N_NODES * 1024 * 2);
    _Float16* h1h  = (_Float16*)alloc((size_t)N_NODES * WIDTH * 2);
    _Float16* xh   = (_Float16*)alloc((size_t)N_NODES * 128 * 2);
    _Float16* Bt1  = (_Float16*)alloc((size_t)1024 * 128 * 2);
    _Float16* Bt2  = (_Float16*)alloc((size_t)1024 * 256 * 2);
    _Float16* ep1  = (_Float16*)alloc((size_t)64 * WIDTH * 2);
    _Float16* ep2  = (_Float16*)alloc((size_t)64 * WIDTH * 2);
    int* cnt = (int*)alloc((size_t)N_NODES * 4);
    int* se  = (int*)alloc((size_t)N_NODES * MAXDEG * 4);

    dim3 node_grid((N_NODES + 3) / 4);
    dim3 gemm_grid((N_NODES + 127) / 128, 8);

    zero_cnt<<<20, 256, 0, stream>>>(cnt);
    prep_all<<<NB_PREP, 256, 0, stream>>>(Wq1, Wk1, Wv1, Wr1,
        Wq2, Wk2, Wv2, Wr2, rel, We1, We2, x, esrc, edst, etyp,
        Bt1, Bt2, ep1, ep2, xh, cnt, se);

    gemm_lds<128><<<gemm_grid, 256, 0, stream>>>(xh, Bt1, QKVR, N_NODES);
    node_attn<false><<<node_grid, 256, 0, stream>>>(QKVR, ep1, cnt, se,
        h1h, nullptr, nullptr, nullptr, nullptr, nullptr, nullptr, N_NODES);

    gemm_lds<256><<<gemm_grid, 256, 0, stream>>>(h1h, Bt2, QKVR, N_NODES);
    node_attn<true><<<node_grid, 256, 0, stream>>>(QKVR, ep2, cnt, se,
        nullptr, Wo, bo, cent, gam, bet, out, N_NODES);
}

// Round 12
// 128.402 us; speedup vs baseline: 1.0900x; 1.0900x over previous
//
#include <hip/hip_runtime.h>
#include <math.h>

#define N_NODES 20000
#define N_EDGES 200000
#define WIDTH   256
#define MAXDEG  64
#define SCALE_F 0.17677669529663687f

typedef _Float16 half8 __attribute__((ext_vector_type(8)));
typedef _Float16 half4 __attribute__((ext_vector_type(4)));
typedef float f32x4 __attribute__((ext_vector_type(4)));

// ---- zero cnt (N_NODES ints = 80 KB) ----
__global__ __launch_bounds__(256) void zero_cnt(int* __restrict__ p)
{
    int i = blockIdx.x * 256 + threadIdx.x;
    if (i < N_NODES / 4) reinterpret_cast<int4*>(p)[i] = make_int4(0, 0, 0, 0);
}

// column remap: q | kv-interleaved(4) | r  within the 1024-wide output row
__device__ __forceinline__ int col_map(int c) {
    if (c < 256 || c >= 768) return c;
    int d = c & 255;
    return 256 + ((d >> 2) << 3) + ((c >= 512) ? 4 : 0) + (d & 3);
}

// ---- fused prep: Bt1, Bt2 (col_map'd rows), ep1, ep2, x->fp16, edge bucketing ----
#define NB_BT1  512
#define NB_BT2  1024
#define NB_EP   64
#define NB_CVT  2500
#define NB_EDGE 782
#define NB_PREP (NB_BT1 + NB_BT2 + 2*NB_EP + NB_CVT + NB_EDGE)

__global__ __launch_bounds__(256) void prep_all(
    const float* __restrict__ Wq1, const float* __restrict__ Wk1,
    const float* __restrict__ Wv1, const float* __restrict__ Wr1,
    const float* __restrict__ Wq2, const float* __restrict__ Wk2,
    const float* __restrict__ Wv2, const float* __restrict__ Wr2,
    const float* __restrict__ rel, const float* __restrict__ We1,
    const float* __restrict__ We2, const float* __restrict__ x,
    const int* __restrict__ esrc, const int* __restrict__ edst,
    const int* __restrict__ etyp,
    _Float16* __restrict__ Bt1, _Float16* __restrict__ Bt2,
    _Float16* __restrict__ ep1, _Float16* __restrict__ ep2,
    _Float16* __restrict__ xh, int* __restrict__ cnt, int* __restrict__ se)
{
    const int b = blockIdx.x, tid = threadIdx.x;
    if (b < NB_BT1) {
        int idx = b * 256 + tid;
        int c = idx >> 7, k = idx & 127;
        const float* W = (c < 256) ? Wq1 : (c < 512) ? Wk1 : (c < 768) ? Wv1 : Wr1;
        Bt1[col_map(c) * 128 + k] = (_Float16)W[k * WIDTH + (c & 255)];
    } else if (b < NB_BT1 + NB_BT2) {
        int idx = (b - NB_BT1) * 256 + tid;
        int c = idx >> 8, k = idx & 255;
        const float* W = (c < 256) ? Wq2 : (c < 512) ? Wk2 : (c < 768) ? Wv2 : Wr2;
        Bt2[col_map(c) * 256 + k] = (_Float16)W[k * WIDTH + (c & 255)];
    } else if (b < NB_BT1 + NB_BT2 + 2 * NB_EP) {
        int lb = b - (NB_BT1 + NB_BT2);
        const float* We = (lb < NB_EP) ? We1 : We2;
        _Float16* ep = (lb < NB_EP) ? ep1 : ep2;
        int r = lb & 63, c = tid;
        float acc = 0.f;
        #pragma unroll
        for (int p = 0; p < 32; ++p) acc += rel[r * 32 + p] * We[p * WIDTH + c];
        ep[r * WIDTH + c] = (_Float16)acc;
    } else if (b < NB_BT1 + NB_BT2 + 2 * NB_EP + NB_CVT) {
        int i = (b - (NB_BT1 + NB_BT2 + 2 * NB_EP)) * 256 + tid;
        float4 v = reinterpret_cast<const float4*>(x)[i];
        half4 h; h[0] = (_Float16)v.x; h[1] = (_Float16)v.y;
        h[2] = (_Float16)v.z; h[3] = (_Float16)v.w;
        reinterpret_cast<half4*>(xh)[i] = h;
    } else {
        // direct fixed-stride bucketing by destination
        int e = (b - (NB_BT1 + NB_BT2 + 2 * NB_EP + NB_CVT)) * 256 + tid;
        if (e < N_EDGES) {
            int d = edst[e];
            int pos = atomicAdd(&cnt[d], 1);
            if (pos < MAXDEG)
                se[d * MAXDEG + pos] = esrc[e] | (etyp[e] << 20);
        }
    }
}

// ---- MFMA fp16 GEMM (round-9 proven shape): 128x128 tile, 256 thr, BK=64 ----
// C[n x 1024] = A[n x K] @ Bt[1024 x K]; Bt rows already col_map-permuted.
// A and B tiles in LDS (XOR-swizzled), reg-prefetch double buffer.
template<int K>
__global__ __launch_bounds__(256) void gemm_lds(const _Float16* __restrict__ A,
    const _Float16* __restrict__ Bt, _Float16* __restrict__ C, int n)
{
    __shared__ __align__(16) _Float16 smem[128 * 128];   // 32 KB
    _Float16* As = smem;          // [128][64] swizzled
    _Float16* Bs = smem + 8192;   // [128][64] swizzled
    const int tid = threadIdx.x;
    const int wave = tid >> 6, lane = tid & 63;
    const int wr = wave >> 1, wc = wave & 1;
    const int row0 = blockIdx.x * 128;
    const int colbase0 = blockIdx.y * 128;
    const int colbase = colbase0 + wc * 64;
    const int lr = lane & 15;
    const int kg = lane >> 4;
    const int srow = tid >> 3;         // 0..31 (+32*s)
    const int scg  = tid & 7;          // 8-half chunk
    f32x4 acc[4][4] = {};
    half8 stgA[4], stgB[4];
    #pragma unroll
    for (int s = 0; s < 4; ++s) {
        int r = srow + s * 32;
        int ar = row0 + r; if (ar >= n) ar = n - 1;
        stgA[s] = *reinterpret_cast<const half8*>(&A[(size_t)ar * K + scg * 8]);
        stgB[s] = *reinterpret_cast<const half8*>(&Bt[(size_t)(colbase0 + r) * K + scg * 8]);
    }
    const int nk = K >> 6;
    for (int t = 0; t < nk; ++t) {
        #pragma unroll
        for (int s = 0; s < 4; ++s) {
            int r = srow + s * 32;
            int sw = (scg * 8) ^ ((r & 7) << 3);
            *reinterpret_cast<half8*>(&As[r * 64 + sw]) = stgA[s];
            *reinterpret_cast<half8*>(&Bs[r * 64 + sw]) = stgB[s];
        }
        __syncthreads();
        if (t + 1 < nk) {
            #pragma unroll
            for (int s = 0; s < 4; ++s) {
                int r = srow + s * 32;
                int ar = row0 + r; if (ar >= n) ar = n - 1;
                stgA[s] = *reinterpret_cast<const half8*>(&A[(size_t)ar * K + (t + 1) * 64 + scg * 8]);
                stgB[s] = *reinterpret_cast<const half8*>(&Bt[(size_t)(colbase0 + r) * K + (t + 1) * 64 + scg * 8]);
            }
        }
        #pragma unroll
        for (int ks = 0; ks < 2; ++ks) {
            half8 a[4], b[4];
            #pragma unroll
            for (int nn = 0; nn < 4; ++nn) {
                int cc = wc * 64 + nn * 16 + lr;
                b[nn] = *reinterpret_cast<const half8*>(&Bs[cc * 64 + ((ks * 32 + kg * 8) ^ ((cc & 7) << 3))]);
            }
            #pragma unroll
            for (int m = 0; m < 4; ++m) {
                int r = wr * 64 + m * 16 + lr;
                a[m] = *reinterpret_cast<const half8*>(&As[r * 64 + ((ks * 32 + kg * 8) ^ ((r & 7) << 3))]);
            }
            // swapped operands: lane holds row lr, 4 consecutive cols per acc reg group
            #pragma unroll
            for (int m = 0; m < 4; ++m)
                #pragma unroll
                for (int nn = 0; nn < 4; ++nn)
                    acc[m][nn] = __builtin_amdgcn_mfma_f32_16x16x32_f16(b[nn], a[m], acc[m][nn], 0, 0, 0);
        }
        __syncthreads();
    }
    // epilogue: per-wave 64x64 fp16 tile in LDS, then coalesced 16B stores
    _Float16* tile = &smem[wave * 4096];
    #pragma unroll
    for (int m = 0; m < 4; ++m) {
        int rr = m * 16 + lr;
        int e = (rr & 7) << 1;
        #pragma unroll
        for (int nn = 0; nn < 4; ++nn) {
            int ch = (nn * 4 + kg) ^ e;
            half4 v4;
            v4[0] = (_Float16)acc[m][nn][0];
            v4[1] = (_Float16)acc[m][nn][1];
            v4[2] = (_Float16)acc[m][nn][2];
            v4[3] = (_Float16)acc[m][nn][3];
            *reinterpret_cast<half4*>(&tile[rr * 64 + ch * 4]) = v4;
        }
    }
    const int cp = lane & 7;
    const int r8 = lane >> 3;
    #pragma unroll
    for (int p = 0; p < 8; ++p) {
        int rr = p * 8 + r8;
        int s = cp ^ (rr & 7);
        half8 v = *reinterpret_cast<const half8*>(&tile[rr * 64 + s * 8]);
        int row = row0 + wr * 64 + rr;
        if (row < n)
            *reinterpret_cast<half8*>(&C[(size_t)row * 1024 + colbase + cp * 8]) = v;
    }
}

// ---- fused per-node flash-style edge softmax, 4-deep unrolled gather ----
// QKVR row (1024 halves): q[0,256) | kv interleaved-by-4 [256,768) | r[768,1024).
// One wave per node; lane l owns dims [4l, 4l+4); head h = l>>3. No LDS (occupancy!).
#define EDGE_DOT(kv, e0, e1, e2, e3, dd)                                     \
    float dd = qx * ((float)kv[0] + e0) + qy * ((float)kv[1] + e1)           \
             + qz * ((float)kv[2] + e2) + qw * ((float)kv[3] + e3);          \
    dd += __shfl_xor(dd, 1); dd += __shfl_xor(dd, 2); dd += __shfl_xor(dd, 4);

template<bool FINAL>
__global__ __launch_bounds__(256) void node_attn(
    const _Float16* __restrict__ QKVR, const _Float16* __restrict__ EP,
    const int* __restrict__ cnt, const int* __restrict__ se,
    _Float16* __restrict__ hout,
    const float* __restrict__ Wo, const float* __restrict__ bo,
    const float* __restrict__ cent, const float* __restrict__ gamma,
    const float* __restrict__ beta, float* __restrict__ out, int n)
{
    int node = blockIdx.x * 4 + (threadIdx.x >> 6);
    if (node >= n) return;
    int lane = threadIdx.x & 63;
    const int l4 = lane * 4, l8 = lane * 8;
    half4 qh = *reinterpret_cast<const half4*>(&QKVR[(size_t)node * 1024 + l4]);
    float qx = qh[0], qy = qh[1], qz = qh[2], qw = qh[3];
    int deg = cnt[node]; if (deg > MAXDEG) deg = MAXDEG;
    const int* lst = &se[node * MAXDEG];
    float m = -INFINITY, s = 0.f;
    float ax = 0.f, ay = 0.f, az = 0.f, aw = 0.f;
    int i = 0;
    for (; i + 3 < deg; i += 4) {
        int4 pp = *reinterpret_cast<const int4*>(&lst[i]);
        int p0 = pp.x, p1 = pp.y, p2 = pp.z, p3 = pp.w;
        half8 kv0 = *reinterpret_cast<const half8*>(&QKVR[(size_t)(p0 & 0xFFFFF) * 1024 + 256 + l8]);
        half8 kv1 = *reinterpret_cast<const half8*>(&QKVR[(size_t)(p1 & 0xFFFFF) * 1024 + 256 + l8]);
        half8 kv2 = *reinterpret_cast<const half8*>(&QKVR[(size_t)(p2 & 0xFFFFF) * 1024 + 256 + l8]);
        half8 kv3 = *reinterpret_cast<const half8*>(&QKVR[(size_t)(p3 & 0xFFFFF) * 1024 + 256 + l8]);
        half4 e0 = *reinterpret_cast<const half4*>(&EP[(p0 >> 20) * WIDTH + l4]);
        half4 e1 = *reinterpret_cast<const half4*>(&EP[(p1 >> 20) * WIDTH + l4]);
        half4 e2 = *reinterpret_cast<const half4*>(&EP[(p2 >> 20) * WIDTH + l4]);
        half4 e3 = *reinterpret_cast<const half4*>(&EP[(p3 >> 20) * WIDTH + l4]);
        float e00 = e0[0], e01 = e0[1], e02 = e0[2], e03 = e0[3];
        float e10 = e1[0], e11 = e1[1], e12 = e1[2], e13 = e1[3];
        float e20 = e2[0], e21 = e2[1], e22 = e2[2], e23 = e2[3];
        float e30 = e3[0], e31 = e3[1], e32 = e3[2], e33 = e3[3];
        EDGE_DOT(kv0, e00, e01, e02, e03, d0)
        EDGE_DOT(kv1, e10, e11, e12, e13, d1)
        EDGE_DOT(kv2, e20, e21, e22, e23, d2)
        EDGE_DOT(kv3, e30, e31, e32, e33, d3)
        float sc0 = d0 * SCALE_F, sc1 = d1 * SCALE_F;
        float sc2 = d2 * SCALE_F, sc3 = d3 * SCALE_F;
        float mnew = fmaxf(m, fmaxf(fmaxf(sc0, sc1), fmaxf(sc2, sc3)));
        float f  = __expf(m - mnew);
        float w0 = __expf(sc0 - mnew);
        float w1 = __expf(sc1 - mnew);
        float w2 = __expf(sc2 - mnew);
        float w3 = __expf(sc3 - mnew);
        s = s * f + (w0 + w1) + (w2 + w3);
        ax = ax * f + w0 * ((float)kv0[4] + e00) + w1 * ((float)kv1[4] + e10)
                    + w2 * ((float)kv2[4] + e20) + w3 * ((float)kv3[4] + e30);
        ay = ay * f + w0 * ((float)kv0[5] + e01) + w1 * ((float)kv1[5] + e11)
                    + w2 * ((float)kv2[5] + e21) + w3 * ((float)kv3[5] + e31);
        az = az * f + w0 * ((float)kv0[6] + e02) + w1 * ((float)kv1[6] + e12)
                    + w2 * ((float)kv2[6] + e22) + w3 * ((float)kv3[6] + e32);
        aw = aw * f + w0 * ((float)kv0[7] + e03) + w1 * ((float)kv1[7] + e13)
                    + w2 * ((float)kv2[7] + e23) + w3 * ((float)kv3[7] + e33);
        m = mnew;
    }
    for (; i + 1 < deg; i += 2) {
        int p0 = lst[i], p1 = lst[i + 1];
        half8 kv0 = *reinterpret_cast<const half8*>(&QKVR[(size_t)(p0 & 0xFFFFF) * 1024 + 256 + l8]);
        half8 kv1 = *reinterpret_cast<const half8*>(&QKVR[(size_t)(p1 & 0xFFFFF) * 1024 + 256 + l8]);
        half4 e0 = *reinterpret_cast<const half4*>(&EP[(p0 >> 20) * WIDTH + l4]);
        half4 e1 = *reinterpret_cast<const half4*>(&EP[(p1 >> 20) * WIDTH + l4]);
        float e00 = e0[0], e01 = e0[1], e02 = e0[2], e03 = e0[3];
        float e10 = e1[0], e11 = e1[1], e12 = e1[2], e13 = e1[3];
        EDGE_DOT(kv0, e00, e01, e02, e03, d0)
        EDGE_DOT(kv1, e10, e11, e12, e13, d1)
        float sc0 = d0 * SCALE_F, sc1 = d1 * SCALE_F;
        float mnew = fmaxf(m, fmaxf(sc0, sc1));
        float f  = __expf(m - mnew);
        float w0 = __expf(sc0 - mnew);
        float w1 = __expf(sc1 - mnew);
        s = s * f + w0 + w1;
        ax = ax * f + w0 * ((float)kv0[4] + e00) + w1 * ((float)kv1[4] + e10);
        ay = ay * f + w0 * ((float)kv0[5] + e01) + w1 * ((float)kv1[5] + e11);
        az = az * f + w0 * ((float)kv0[6] + e02) + w1 * ((float)kv1[6] + e12);
        aw = aw * f + w0 * ((float)kv0[7] + e03) + w1 * ((float)kv1[7] + e13);
        m = mnew;
    }
    if (i < deg) {
        int p0 = lst[i];
        half8 kv0 = *reinterpret_cast<const half8*>(&QKVR[(size_t)(p0 & 0xFFFFF) * 1024 + 256 + l8]);
        half4 e0 = *reinterpret_cast<const half4*>(&EP[(p0 >> 20) * WIDTH + l4]);
        float e00 = e0[0], e01 = e0[1], e02 = e0[2], e03 = e0[3];
        EDGE_DOT(kv0, e00, e01, e02, e03, d0)
        float sc0 = d0 * SCALE_F;
        float mnew = fmaxf(m, sc0);
        float f  = __expf(m - mnew);
        float w0 = __expf(sc0 - mnew);
        s = s * f + w0;
        ax = ax * f + w0 * ((float)kv0[4] + e00);
        ay = ay * f + w0 * ((float)kv0[5] + e01);
        az = az * f + w0 * ((float)kv0[6] + e02);
        aw = aw * f + w0 * ((float)kv0[7] + e03);
        m = mnew;
    }
    float inv = 1.f / (s + 1e-9f);
    half4 rh = *reinterpret_cast<const half4*>(&QKVR[(size_t)node * 1024 + 768 + l4]);
    float h0 = ax * inv + (float)rh[0];
    float h1 = ay * inv + (float)rh[1];
    float h2 = az * inv + (float)rh[2];
    float h3 = aw * inv + (float)rh[3];
    h0 = h0 > 0.f ? h0 : __expf(h0) - 1.f;
    h1 = h1 > 0.f ? h1 : __expf(h1) - 1.f;
    h2 = h2 > 0.f ? h2 : __expf(h2) - 1.f;
    h3 = h3 > 0.f ? h3 : __expf(h3) - 1.f;
    if (FINAL) {
        float4 wv = *reinterpret_cast<const float4*>(&Wo[l4]);
        float p = h0 * wv.x + h1 * wv.y + h2 * wv.z + h3 * wv.w;
        #pragma unroll
        for (int o = 1; o < 64; o <<= 1) p += __shfl_xor(p, o);
        if (lane == 0) {
            float logit = p + bo[0];
            float scale = cent[node] * gamma[0] + beta[0];
            out[node] = fmaxf(scale * logit, 0.f);
        }
    } else {
        half4 hv;
        hv[0] = (_Float16)h0; hv[1] = (_Float16)h1;
        hv[2] = (_Float16)h2; hv[3] = (_Float16)h3;
        *reinterpret_cast<half4*>(&hout[(size_t)node * WIDTH + l4]) = hv;
    }
}

extern "C" void kernel_launch(void* const* d_in, const int* in_sizes, int n_in,
                              void* d_out, int out_size, void* d_ws, size_t ws_size,
                              hipStream_t stream) {
    const float* x    = (const float*)d_in[0];
    const float* cent = (const float*)d_in[1];
    const float* rel  = (const float*)d_in[2];
    const float* Wq1  = (const float*)d_in[3];
    const float* Wk1  = (const float*)d_in[4];
    const float* Wv1  = (const float*)d_in[5];
    const float* We1  = (const float*)d_in[6];
    const float* Wr1  = (const float*)d_in[7];
    const float* Wq2  = (const float*)d_in[8];
    const float* Wk2  = (const float*)d_in[9];
    const float* Wv2  = (const float*)d_in[10];
    const float* We2  = (const float*)d_in[11];
    const float* Wr2  = (const float*)d_in[12];
    const float* Wo   = (const float*)d_in[13];
    const float* bo   = (const float*)d_in[14];
    const float* gam  = (const float*)d_in[15];
    const float* bet  = (const float*)d_in[16];
    const int* esrc   = (const int*)d_in[17];
    const int* edst   = (const int*)d_in[18];
    const int* etyp   = (const int*)d_in[19];
    float* out = (float*)d_out;

    char* wsb = (char*)d_ws;
    size_t off = 0;
    auto alloc = [&](size_t bytes) { void* p = wsb + off; off += (bytes + 255) & ~(size_t)255; return p; };
    _Float16* QKVR = (_Float16*)alloc((size_t)N_NODES * 1024 * 2);
    _Float16* h1h  = (_Float16*)alloc((size_t)N_NODES * WIDTH * 2);
    _Float16* xh   = (_Float16*)alloc((size_t)N_NODES * 128 * 2);
    _Float16* Bt1  = (_Float16*)alloc((size_t)1024 * 128 * 2);
    _Float16* Bt2  = (_Float16*)alloc((size_t)1024 * 256 * 2);
    _Float16* ep1  = (_Float16*)alloc((size_t)64 * WIDTH * 2);
    _Float16* ep2  = (_Float16*)alloc((size_t)64 * WIDTH * 2);
    int* cnt = (int*)alloc((size_t)N_NODES * 4);
    int* se  = (int*)alloc((size_t)N_NODES * MAXDEG * 4);

    dim3 node_grid((N_NODES + 3) / 4);
    dim3 gemm_grid((N_NODES + 127) / 128, 8);

    zero_cnt<<<20, 256, 0, stream>>>(cnt);
    prep_all<<<NB_PREP, 256, 0, stream>>>(Wq1, Wk1, Wv1, Wr1,
        Wq2, Wk2, Wv2, Wr2, rel, We1, We2, x, esrc, edst, etyp,
        Bt1, Bt2, ep1, ep2, xh, cnt, se);

    gemm_lds<128><<<gemm_grid, 256, 0, stream>>>(xh, Bt1, QKVR, N_NODES);
    node_attn<false><<<node_grid, 256, 0, stream>>>(QKVR, ep1, cnt, se,
        h1h, nullptr, nullptr, nullptr, nullptr, nullptr, nullptr, N_NODES);

    gemm_lds<256><<<gemm_grid, 256, 0, stream>>>(h1h, Bt2, QKVR, N_NODES);
    node_attn<true><<<node_grid, 256, 0, stream>>>(QKVR, ep2, cnt, se,
        nullptr, Wo, bo, cent, gam, bet, out, N_NODES);
}